// Round 1
// baseline (1549.822 us; speedup 1.0000x reference)
//
#include <hip/hip_runtime.h>
#include <hip/hip_bf16.h>
#include <cstddef>

// Problem constants (validated against in_sizes at runtime)
#define CH 128
#define BN_EPS 1e-5f

// ---------------------------------------------------------------------------
// Workspace layout (bytes):
//   cnt      : N * 4            (int degree counts, zeroed each call)
//   dinv     : N * 4            (float rsqrt(deg))
//   small    : 4096             (sums1, sumsq1, sums2, sumsq2, scale1, shift1,
//                                scale2, shift2 -- 8 x 128 floats)
//   h_buf    : N * 128 * 4      (post-GEMM features)
//   agg_buf  : N * 128 * 4      (post-aggregation features)
// Total ~103.3 MB.
// ---------------------------------------------------------------------------

__global__ void count_kernel(const int* __restrict__ dst, int* __restrict__ cnt, int E) {
    int e = blockIdx.x * 256 + threadIdx.x;
    if (e < E) atomicAdd(&cnt[dst[e]], 1);
}

__global__ void dinv_kernel(const int* __restrict__ cnt, float* __restrict__ dinv, int n) {
    int i = blockIdx.x * 256 + threadIdx.x;
    if (i < n) dinv[i] = rsqrtf((float)cnt[i] + 1.0f);  // +1 = self loop
}

// Per-channel sum & sumsq over rows. Optional pre-op: v = relu(v + bias[c]).
__global__ __launch_bounds__(256) void stats_kernel(
    const float* __restrict__ in, const float* __restrict__ bias, int do_relu,
    float* __restrict__ sums, float* __restrict__ sumsq, int n) {
    int c = threadIdx.x & (CH - 1);
    int rstart = blockIdx.x * 2 + (threadIdx.x >> 7);
    int rstride = gridDim.x * 2;
    float bc = do_relu ? bias[c] : 0.0f;
    float s = 0.f, s2 = 0.f;
    for (int r = rstart; r < n; r += rstride) {
        float v = in[(size_t)r * CH + c];
        if (do_relu) v = fmaxf(v + bc, 0.f);
        s += v; s2 += v * v;
    }
    __shared__ float ls[256], ls2[256];
    ls[threadIdx.x] = s; ls2[threadIdx.x] = s2;
    __syncthreads();
    if (threadIdx.x < CH) {
        unsafeAtomicAdd(&sums[c],  ls[threadIdx.x] + ls[threadIdx.x + CH]);
        unsafeAtomicAdd(&sumsq[c], ls2[threadIdx.x] + ls2[threadIdx.x + CH]);
    }
}

// scale/shift so that BN(v) = v*scale[c] + shift[c]
__global__ void bnparam_kernel(const float* __restrict__ sums, const float* __restrict__ sumsq,
                               const float* __restrict__ gamma, const float* __restrict__ beta,
                               float* __restrict__ scale, float* __restrict__ shift, int n) {
    int c = threadIdx.x;
    if (c >= CH) return;
    float inv_n = 1.0f / (float)n;
    float mean = sums[c] * inv_n;
    float var  = sumsq[c] * inv_n - mean * mean;  // biased variance
    float sc = gamma[c] * rsqrtf(var + BN_EPS);
    scale[c] = sc;
    shift[c] = beta[c] - mean * sc;
}

// C[row, j] = sum_k pre(A[row,k]) * W[j,k]
// pre(v) = (do_relu ? relu(v + bias[k]) : v) * scale[k] + shift[k]
// Tile: 128 rows x 128 cols per block, 256 threads, 8x8 micro-tile, KC=32.
#define GT 128
#define GKC 32
__global__ __launch_bounds__(256) void gemm_bn_kernel(
    const float* __restrict__ A, const float* __restrict__ bias, int do_relu,
    const float* __restrict__ scale, const float* __restrict__ shift,
    const float* __restrict__ W, float* __restrict__ C, int n) {
    __shared__ float As[GT][GKC + 1];  // [row][k]
    __shared__ float Bs[GT][GKC + 1];  // [col j][k]
    int tid = threadIdx.x;
    int tx = tid & 15, ty = tid >> 4;
    int row0 = blockIdx.x * GT;
    float acc[8][8] = {};
    for (int kc = 0; kc < CH; kc += GKC) {
        #pragma unroll
        for (int p = 0; p < 16; ++p) {
            int idx = p * 256 + tid;
            int ar = idx >> 5, ak = idx & 31;
            int row = row0 + ar, ch = kc + ak;
            float v = 0.f;
            if (row < n) {
                v = A[(size_t)row * CH + ch];
                if (do_relu) v = fmaxf(v + bias[ch], 0.f);
                v = v * scale[ch] + shift[ch];
            }
            As[ar][ak] = v;
            Bs[ar][ak] = W[(size_t)ar * CH + ch];  // ar doubles as output col j
        }
        __syncthreads();
        #pragma unroll
        for (int kk = 0; kk < GKC; ++kk) {
            float a[8], b[8];
            #pragma unroll
            for (int i = 0; i < 8; ++i) a[i] = As[ty * 8 + i][kk];
            #pragma unroll
            for (int j = 0; j < 8; ++j) b[j] = Bs[tx * 8 + j][kk];
            #pragma unroll
            for (int i = 0; i < 8; ++i)
                #pragma unroll
                for (int j = 0; j < 8; ++j) acc[i][j] += a[i] * b[j];
        }
        __syncthreads();
    }
    #pragma unroll
    for (int i = 0; i < 8; ++i) {
        int row = row0 + ty * 8 + i;
        if (row >= n) break;
        #pragma unroll
        for (int j = 0; j < 8; j += 4) {
            float4 v = make_float4(acc[i][j], acc[i][j+1], acc[i][j+2], acc[i][j+3]);
            *(float4*)&C[(size_t)row * CH + tx * 8 + j] = v;
        }
    }
}

// agg[i] = h[i] * dinv[i]^2   (the self-loop term; doubles as the zero-init)
__global__ void init_agg_kernel(const float* __restrict__ h, const float* __restrict__ dinv,
                                float* __restrict__ agg, int n) {
    int idx = blockIdx.x * 256 + threadIdx.x;  // over n*32 float4s
    if (idx >= n * (CH / 4)) return;
    int i = idx >> 5;
    float di = dinv[i];
    float w = di * di;
    float4 v = ((const float4*)h)[idx];
    v.x *= w; v.y *= w; v.z *= w; v.w *= w;
    ((float4*)agg)[idx] = v;
}

// Edge scatter: agg[dst] += h[src] * dinv[src]*dinv[dst].  2 edges / 256-thread block.
__global__ __launch_bounds__(256) void scatter_kernel(
    const float* __restrict__ h, const int* __restrict__ src, const int* __restrict__ dst,
    const float* __restrict__ dinv, float* __restrict__ agg, int E) {
    int e = blockIdx.x * 2 + (threadIdx.x >> 7);
    if (e >= E) return;
    int c = threadIdx.x & (CH - 1);
    int s = src[e], d = dst[e];
    float norm = dinv[s] * dinv[d];
    unsafeAtomicAdd(&agg[(size_t)d * CH + c], h[(size_t)s * CH + c] * norm);
}

// out = relu(agg + b2) + x
__global__ void final_kernel(const float* __restrict__ agg, const float* __restrict__ x,
                             const float* __restrict__ b2, float* __restrict__ out, int n) {
    int idx = blockIdx.x * 256 + threadIdx.x;  // over n*32 float4s
    if (idx >= n * (CH / 4)) return;
    int c4 = (idx & 31) * 4;
    float4 v = ((const float4*)agg)[idx];
    float4 xb = ((const float4*)x)[idx];
    float4 o;
    o.x = fmaxf(v.x + b2[c4 + 0], 0.f) + xb.x;
    o.y = fmaxf(v.y + b2[c4 + 1], 0.f) + xb.y;
    o.z = fmaxf(v.z + b2[c4 + 2], 0.f) + xb.z;
    o.w = fmaxf(v.w + b2[c4 + 3], 0.f) + xb.w;
    ((float4*)out)[idx] = o;
}

extern "C" void kernel_launch(void* const* d_in, const int* in_sizes, int n_in,
                              void* d_out, int out_size, void* d_ws, size_t ws_size,
                              hipStream_t stream) {
    const float* x      = (const float*)d_in[0];
    const int*   eidx   = (const int*)d_in[1];
    const float* W1     = (const float*)d_in[2];
    const float* b1     = (const float*)d_in[3];
    const float* W2     = (const float*)d_in[4];
    const float* b2     = (const float*)d_in[5];
    const float* gamma1 = (const float*)d_in[6];
    const float* beta1  = (const float*)d_in[7];
    const float* gamma2 = (const float*)d_in[8];
    const float* beta2  = (const float*)d_in[9];
    float* out = (float*)d_out;

    const int N = in_sizes[0] / CH;
    const int E = in_sizes[1] / 2;
    const int* src = eidx;
    const int* dst = eidx + E;

    // workspace carve-up
    char* ws = (char*)d_ws;
    size_t off = 0;
    auto carve = [&](size_t bytes) { char* p = ws + off; off = (off + bytes + 1023) & ~(size_t)1023; return p; };
    int*   cnt   = (int*)carve((size_t)N * 4);
    float* dinv  = (float*)carve((size_t)N * 4);
    float* small = (float*)carve(8 * CH * 4);
    float* sums1  = small + 0 * CH;
    float* sumsq1 = small + 1 * CH;
    float* sums2  = small + 2 * CH;
    float* sumsq2 = small + 3 * CH;
    float* scale1 = small + 4 * CH;
    float* shift1 = small + 5 * CH;
    float* scale2 = small + 6 * CH;
    float* shift2 = small + 7 * CH;
    float* h_buf   = (float*)carve((size_t)N * CH * 4);
    float* agg_buf = (float*)carve((size_t)N * CH * 4);
    (void)ws_size; (void)n_in; (void)out_size;

    hipMemsetAsync(cnt, 0, (size_t)N * 4, stream);
    hipMemsetAsync(small, 0, 8 * CH * 4, stream);

    count_kernel<<<(E + 255) / 256, 256, 0, stream>>>(dst, cnt, E);
    dinv_kernel<<<(N + 255) / 256, 256, 0, stream>>>(cnt, dinv, N);

    // ---- stage 1 ----
    stats_kernel<<<784, 256, 0, stream>>>(x, nullptr, 0, sums1, sumsq1, N);
    bnparam_kernel<<<1, CH, 0, stream>>>(sums1, sumsq1, gamma1, beta1, scale1, shift1, N);
    gemm_bn_kernel<<<(N + GT - 1) / GT, 256, 0, stream>>>(x, nullptr, 0, scale1, shift1, W1, h_buf, N);
    init_agg_kernel<<<(N * (CH / 4) + 255) / 256, 256, 0, stream>>>(h_buf, dinv, agg_buf, N);
    scatter_kernel<<<(E + 1) / 2, 256, 0, stream>>>(h_buf, src, dst, dinv, agg_buf, E);

    // ---- stage 2 ----
    stats_kernel<<<784, 256, 0, stream>>>(agg_buf, b1, 1, sums2, sumsq2, N);
    bnparam_kernel<<<1, CH, 0, stream>>>(sums2, sumsq2, gamma2, beta2, scale2, shift2, N);
    gemm_bn_kernel<<<(N + GT - 1) / GT, 256, 0, stream>>>(agg_buf, b1, 1, scale2, shift2, W2, h_buf, N);
    init_agg_kernel<<<(N * (CH / 4) + 255) / 256, 256, 0, stream>>>(h_buf, dinv, agg_buf, N);
    scatter_kernel<<<(E + 1) / 2, 256, 0, stream>>>(h_buf, src, dst, dinv, agg_buf, E);

    final_kernel<<<(N * (CH / 4) + 255) / 256, 256, 0, stream>>>(agg_buf, x, b2, out, N);
}

// Round 2
// 1106.498 us; speedup vs baseline: 1.4007x; 1.4007x over previous
//
#include <hip/hip_runtime.h>
#include <hip/hip_bf16.h>
#include <cstddef>

#define CH 128
#define BN_EPS 1e-5f

// ---------------------------------------------------------------------------
// Strategy (R2): CSR gather-aggregation instead of atomic scatter.
// R1 counters: scatter_kernel 2x426us, WRITE_SIZE=500MB (= E*128*4B atomic
// write-through), the dominant cost. Gather form writes 51MB non-atomically
// and reads h (51MB, LLC-resident) randomly -> L2/L3 absorbs.
// ---------------------------------------------------------------------------

__global__ void count_kernel(const int* __restrict__ dst, int* __restrict__ cnt, int E) {
    int e = blockIdx.x * 256 + threadIdx.x;
    if (e < E) atomicAdd(&cnt[dst[e]], 1);
}

__global__ void dinv_kernel(const int* __restrict__ cnt, float* __restrict__ dinv, int n) {
    int i = blockIdx.x * 256 + threadIdx.x;
    if (i < n) dinv[i] = rsqrtf((float)cnt[i] + 1.0f);  // +1 = self loop
}

// Exclusive scan, 3 kernels: per-1024-block scan, block-sum scan, add-back.
__global__ __launch_bounds__(256) void scan1_kernel(const int* __restrict__ cnt,
                                                    int* __restrict__ offs,
                                                    int* __restrict__ bsum, int n) {
    __shared__ int sd[256];
    int t = threadIdx.x;
    int base = blockIdx.x * 1024 + t * 4;
    int v[4];
    #pragma unroll
    for (int j = 0; j < 4; ++j) v[j] = (base + j < n) ? cnt[base + j] : 0;
    int s = v[0] + v[1] + v[2] + v[3];
    sd[t] = s;
    __syncthreads();
    for (int off = 1; off < 256; off <<= 1) {
        int x = (t >= off) ? sd[t - off] : 0;
        __syncthreads();
        sd[t] += x;
        __syncthreads();
    }
    int run = sd[t] - s;  // exclusive prefix within block
    #pragma unroll
    for (int j = 0; j < 4; ++j) {
        if (base + j < n) offs[base + j] = run;
        run += v[j];
    }
    if (t == 255) bsum[blockIdx.x] = sd[255];
}

__global__ __launch_bounds__(256) void scan2_kernel(int* __restrict__ bsum, int nb) {
    __shared__ int sd[256];
    int t = threadIdx.x;
    int base = t * 4;
    int v[4];
    #pragma unroll
    for (int j = 0; j < 4; ++j) v[j] = (base + j < nb) ? bsum[base + j] : 0;
    int s = v[0] + v[1] + v[2] + v[3];
    sd[t] = s;
    __syncthreads();
    for (int off = 1; off < 256; off <<= 1) {
        int x = (t >= off) ? sd[t - off] : 0;
        __syncthreads();
        sd[t] += x;
        __syncthreads();
    }
    int run = sd[t] - s;
    #pragma unroll
    for (int j = 0; j < 4; ++j) {
        if (base + j < nb) bsum[base + j] = run;
        run += v[j];
    }
}

__global__ void scan3_kernel(int* __restrict__ offs, const int* __restrict__ bsum,
                             int n, int E) {
    int i = blockIdx.x * 256 + threadIdx.x;
    if (i < n) offs[i] += bsum[i >> 10];
    if (i == 0) offs[n] = E;
}

// Bucket edges by dst; store src id and precomputed norm = dinv[s]*dinv[d].
__global__ void fill_kernel(const int* __restrict__ src, const int* __restrict__ dst,
                            const int* __restrict__ offs, int* __restrict__ fillc,
                            const float* __restrict__ dinv,
                            int* __restrict__ csr_src, float* __restrict__ csr_norm, int E) {
    int e = blockIdx.x * 256 + threadIdx.x;
    if (e >= E) return;
    int s = src[e], d = dst[e];
    int p = offs[d] + atomicAdd(&fillc[d], 1);
    csr_src[p] = s;
    csr_norm[p] = dinv[s] * dinv[d];
}

// Per-channel sum & sumsq over rows. Optional pre-op: v = relu(v + bias[c]).
__global__ __launch_bounds__(256) void stats_kernel(
    const float* __restrict__ in, const float* __restrict__ bias, int do_relu,
    float* __restrict__ sums, float* __restrict__ sumsq, int n) {
    int c = threadIdx.x & (CH - 1);
    int rstart = blockIdx.x * 2 + (threadIdx.x >> 7);
    int rstride = gridDim.x * 2;
    float bc = do_relu ? bias[c] : 0.0f;
    float s = 0.f, s2 = 0.f;
    for (int r = rstart; r < n; r += rstride) {
        float v = in[(size_t)r * CH + c];
        if (do_relu) v = fmaxf(v + bc, 0.f);
        s += v; s2 += v * v;
    }
    __shared__ float ls[256], ls2[256];
    ls[threadIdx.x] = s; ls2[threadIdx.x] = s2;
    __syncthreads();
    if (threadIdx.x < CH) {
        unsafeAtomicAdd(&sums[c],  ls[threadIdx.x] + ls[threadIdx.x + CH]);
        unsafeAtomicAdd(&sumsq[c], ls2[threadIdx.x] + ls2[threadIdx.x + CH]);
    }
}

__global__ void bnparam_kernel(const float* __restrict__ sums, const float* __restrict__ sumsq,
                               const float* __restrict__ gamma, const float* __restrict__ beta,
                               float* __restrict__ scale, float* __restrict__ shift, int n) {
    int c = threadIdx.x;
    if (c >= CH) return;
    float inv_n = 1.0f / (float)n;
    float mean = sums[c] * inv_n;
    float var  = sumsq[c] * inv_n - mean * mean;  // biased variance
    float sc = gamma[c] * rsqrtf(var + BN_EPS);
    scale[c] = sc;
    shift[c] = beta[c] - mean * sc;
}

// C[row, j] = sum_k pre(A[row,k]) * W[j,k]
// pre(v) = (do_relu ? relu(v + bias[k]) : v) * scale[k] + shift[k]
#define GT 128
#define GKC 32
__global__ __launch_bounds__(256) void gemm_bn_kernel(
    const float* __restrict__ A, const float* __restrict__ bias, int do_relu,
    const float* __restrict__ scale, const float* __restrict__ shift,
    const float* __restrict__ W, float* __restrict__ C, int n) {
    __shared__ float As[GT][GKC + 1];
    __shared__ float Bs[GT][GKC + 1];
    int tid = threadIdx.x;
    int tx = tid & 15, ty = tid >> 4;
    int row0 = blockIdx.x * GT;
    float acc[8][8] = {};
    for (int kc = 0; kc < CH; kc += GKC) {
        #pragma unroll
        for (int p = 0; p < 16; ++p) {
            int idx = p * 256 + tid;
            int ar = idx >> 5, ak = idx & 31;
            int row = row0 + ar, ch = kc + ak;
            float v = 0.f;
            if (row < n) {
                v = A[(size_t)row * CH + ch];
                if (do_relu) v = fmaxf(v + bias[ch], 0.f);
                v = v * scale[ch] + shift[ch];
            }
            As[ar][ak] = v;
            Bs[ar][ak] = W[(size_t)ar * CH + ch];
        }
        __syncthreads();
        #pragma unroll
        for (int kk = 0; kk < GKC; ++kk) {
            float a[8], b[8];
            #pragma unroll
            for (int i = 0; i < 8; ++i) a[i] = As[ty * 8 + i][kk];
            #pragma unroll
            for (int j = 0; j < 8; ++j) b[j] = Bs[tx * 8 + j][kk];
            #pragma unroll
            for (int i = 0; i < 8; ++i)
                #pragma unroll
                for (int j = 0; j < 8; ++j) acc[i][j] += a[i] * b[j];
        }
        __syncthreads();
    }
    #pragma unroll
    for (int i = 0; i < 8; ++i) {
        int row = row0 + ty * 8 + i;
        if (row >= n) break;
        #pragma unroll
        for (int j = 0; j < 8; j += 4) {
            float4 v = make_float4(acc[i][j], acc[i][j+1], acc[i][j+2], acc[i][j+3]);
            *(float4*)&C[(size_t)row * CH + tx * 8 + j] = v;
        }
    }
}

// Gather aggregation: one node per 128 threads (2 nodes / block).
// acc = h[node]*dinv^2 + sum_e h[csr_src[e]] * csr_norm[e]
// final_mode: out = relu(acc + bias) + x   else: out = acc
__global__ __launch_bounds__(256) void agg_gather_kernel(
    const float* __restrict__ h, const int* __restrict__ csr_src,
    const float* __restrict__ csr_norm, const int* __restrict__ offs,
    const float* __restrict__ dinv, const float* __restrict__ bias,
    const float* __restrict__ x, float* __restrict__ outbuf, int n, int final_mode) {
    int node = blockIdx.x * 2 + (threadIdx.x >> 7);
    if (node >= n) return;
    int c = threadIdx.x & (CH - 1);
    float di = dinv[node];
    float acc = h[(size_t)node * CH + c] * di * di;
    int beg = offs[node], end = offs[node + 1];
    for (int e = beg; e < end; ++e) {
        int s = csr_src[e];
        float nrm = csr_norm[e];
        acc += h[(size_t)s * CH + c] * nrm;
    }
    size_t o = (size_t)node * CH + c;
    if (final_mode) {
        outbuf[o] = fmaxf(acc + bias[c], 0.f) + x[o];
    } else {
        outbuf[o] = acc;
    }
}

extern "C" void kernel_launch(void* const* d_in, const int* in_sizes, int n_in,
                              void* d_out, int out_size, void* d_ws, size_t ws_size,
                              hipStream_t stream) {
    const float* x      = (const float*)d_in[0];
    const int*   eidx   = (const int*)d_in[1];
    const float* W1     = (const float*)d_in[2];
    const float* b1     = (const float*)d_in[3];
    const float* W2     = (const float*)d_in[4];
    const float* b2     = (const float*)d_in[5];
    const float* gamma1 = (const float*)d_in[6];
    const float* beta1  = (const float*)d_in[7];
    const float* gamma2 = (const float*)d_in[8];
    const float* beta2  = (const float*)d_in[9];
    float* out = (float*)d_out;

    const int N = in_sizes[0] / CH;
    const int E = in_sizes[1] / 2;
    const int* src = eidx;
    const int* dst = eidx + E;

    char* ws = (char*)d_ws;
    size_t off = 0;
    auto carve = [&](size_t bytes) { char* p = ws + off; off = (off + bytes + 1023) & ~(size_t)1023; return p; };
    int*   cnt     = (int*)carve((size_t)N * 4);
    float* dinv    = (float*)carve((size_t)N * 4);
    int*   offs    = (int*)carve((size_t)(N + 1) * 4);
    int*   fillc   = (int*)carve((size_t)N * 4);
    int*   bsum    = (int*)carve(1024 * 4);
    float* small   = (float*)carve(8 * CH * 4);
    int*   csr_src = (int*)carve((size_t)E * 4);
    float* csr_nrm = (float*)carve((size_t)E * 4);
    float* h_buf   = (float*)carve((size_t)N * CH * 4);
    float* agg_buf = (float*)carve((size_t)N * CH * 4);
    float* sums1  = small + 0 * CH;
    float* sumsq1 = small + 1 * CH;
    float* sums2  = small + 2 * CH;
    float* sumsq2 = small + 3 * CH;
    float* scale1 = small + 4 * CH;
    float* shift1 = small + 5 * CH;
    float* scale2 = small + 6 * CH;
    float* shift2 = small + 7 * CH;
    (void)ws_size; (void)n_in; (void)out_size;

    hipMemsetAsync(cnt, 0, (size_t)N * 4, stream);
    hipMemsetAsync(fillc, 0, (size_t)N * 4, stream);
    hipMemsetAsync(small, 0, 8 * CH * 4, stream);

    // ---- graph prep: degrees + CSR ----
    count_kernel<<<(E + 255) / 256, 256, 0, stream>>>(dst, cnt, E);
    dinv_kernel<<<(N + 255) / 256, 256, 0, stream>>>(cnt, dinv, N);
    int nb = (N + 1023) / 1024;
    scan1_kernel<<<nb, 256, 0, stream>>>(cnt, offs, bsum, N);
    scan2_kernel<<<1, 256, 0, stream>>>(bsum, nb);
    scan3_kernel<<<(N + 255) / 256, 256, 0, stream>>>(offs, bsum, N, E);
    fill_kernel<<<(E + 255) / 256, 256, 0, stream>>>(src, dst, offs, fillc, dinv, csr_src, csr_nrm, E);

    // ---- stage 1 ----
    stats_kernel<<<784, 256, 0, stream>>>(x, nullptr, 0, sums1, sumsq1, N);
    bnparam_kernel<<<1, CH, 0, stream>>>(sums1, sumsq1, gamma1, beta1, scale1, shift1, N);
    gemm_bn_kernel<<<(N + GT - 1) / GT, 256, 0, stream>>>(x, nullptr, 0, scale1, shift1, W1, h_buf, N);
    agg_gather_kernel<<<(N + 1) / 2, 256, 0, stream>>>(h_buf, csr_src, csr_nrm, offs, dinv,
                                                       nullptr, nullptr, agg_buf, N, 0);

    // ---- stage 2 (final epilogue fused into aggregation) ----
    stats_kernel<<<784, 256, 0, stream>>>(agg_buf, b1, 1, sums2, sumsq2, N);
    bnparam_kernel<<<1, CH, 0, stream>>>(sums2, sumsq2, gamma2, beta2, scale2, shift2, N);
    gemm_bn_kernel<<<(N + GT - 1) / GT, 256, 0, stream>>>(agg_buf, b1, 1, scale2, shift2, W2, h_buf, N);
    agg_gather_kernel<<<(N + 1) / 2, 256, 0, stream>>>(h_buf, csr_src, csr_nrm, offs, dinv,
                                                       b2, x, out, N, 1);
}

// Round 3
// 490.477 us; speedup vs baseline: 3.1598x; 2.2560x over previous
//
#include <hip/hip_runtime.h>
#include <hip/hip_bf16.h>
#include <cstddef>

#define CH 128
#define BN_EPS 1e-5f

typedef __bf16 bf16x8 __attribute__((ext_vector_type(8)));
typedef __bf16 bf16x4 __attribute__((ext_vector_type(4)));
typedef float  f32x4  __attribute__((ext_vector_type(4)));

__device__ inline float bf2f(__bf16 b) { return (float)b; }

// ---------------------------------------------------------------------------
// R3: bf16-MFMA GEMM (BN folded into A-staging) + bf16 h for the gather.
// R2 counters: gemm_bn 2x232us latency-bound (VALUBusy 13%, occ 9%, 1.4e7 LDS
// conflicts); agg ~remaining 600us. MFMA floor ~12us/GEMM (77MB HBM);
// bf16 h halves gather bytes.
// ---------------------------------------------------------------------------

__global__ void count_kernel(const int* __restrict__ dst, int* __restrict__ cnt, int E) {
    int e = blockIdx.x * 256 + threadIdx.x;
    if (e < E) atomicAdd(&cnt[dst[e]], 1);
}

__global__ void dinv_kernel(const int* __restrict__ cnt, float* __restrict__ dinv, int n) {
    int i = blockIdx.x * 256 + threadIdx.x;
    if (i < n) dinv[i] = rsqrtf((float)cnt[i] + 1.0f);  // +1 = self loop
}

__global__ __launch_bounds__(256) void scan1_kernel(const int* __restrict__ cnt,
                                                    int* __restrict__ offs,
                                                    int* __restrict__ bsum, int n) {
    __shared__ int sd[256];
    int t = threadIdx.x;
    int base = blockIdx.x * 1024 + t * 4;
    int v[4];
    #pragma unroll
    for (int j = 0; j < 4; ++j) v[j] = (base + j < n) ? cnt[base + j] : 0;
    int s = v[0] + v[1] + v[2] + v[3];
    sd[t] = s;
    __syncthreads();
    for (int off = 1; off < 256; off <<= 1) {
        int x = (t >= off) ? sd[t - off] : 0;
        __syncthreads();
        sd[t] += x;
        __syncthreads();
    }
    int run = sd[t] - s;
    #pragma unroll
    for (int j = 0; j < 4; ++j) {
        if (base + j < n) offs[base + j] = run;
        run += v[j];
    }
    if (t == 255) bsum[blockIdx.x] = sd[255];
}

__global__ __launch_bounds__(256) void scan2_kernel(int* __restrict__ bsum, int nb) {
    __shared__ int sd[256];
    int t = threadIdx.x;
    int base = t * 4;
    int v[4];
    #pragma unroll
    for (int j = 0; j < 4; ++j) v[j] = (base + j < nb) ? bsum[base + j] : 0;
    int s = v[0] + v[1] + v[2] + v[3];
    sd[t] = s;
    __syncthreads();
    for (int off = 1; off < 256; off <<= 1) {
        int x = (t >= off) ? sd[t - off] : 0;
        __syncthreads();
        sd[t] += x;
        __syncthreads();
    }
    int run = sd[t] - s;
    #pragma unroll
    for (int j = 0; j < 4; ++j) {
        if (base + j < nb) bsum[base + j] = run;
        run += v[j];
    }
}

__global__ void scan3_kernel(int* __restrict__ offs, const int* __restrict__ bsum,
                             int n, int E) {
    int i = blockIdx.x * 256 + threadIdx.x;
    if (i < n) offs[i] += bsum[i >> 10];
    if (i == 0) offs[n] = E;
}

__global__ void fill_kernel(const int* __restrict__ src, const int* __restrict__ dst,
                            const int* __restrict__ offs, int* __restrict__ fillc,
                            const float* __restrict__ dinv,
                            int* __restrict__ csr_src, float* __restrict__ csr_norm, int E) {
    int e = blockIdx.x * 256 + threadIdx.x;
    if (e >= E) return;
    int s = src[e], d = dst[e];
    int p = offs[d] + atomicAdd(&fillc[d], 1);
    csr_src[p] = s;
    csr_norm[p] = dinv[s] * dinv[d];
}

__global__ void wprep_kernel(const float* __restrict__ W, __bf16* __restrict__ Wb, int total) {
    int i = blockIdx.x * 256 + threadIdx.x;
    if (i < total) Wb[i] = (__bf16)W[i];
}

// Per-channel sum & sumsq over rows. Optional pre-op: v = relu(v + bias[c]).
__global__ __launch_bounds__(256) void stats_kernel(
    const float* __restrict__ in, const float* __restrict__ bias, int do_relu,
    float* __restrict__ sums, float* __restrict__ sumsq, int n) {
    int c = threadIdx.x & (CH - 1);
    int rstart = blockIdx.x * 2 + (threadIdx.x >> 7);
    int rstride = gridDim.x * 2;
    float bc = do_relu ? bias[c] : 0.0f;
    float s = 0.f, s2 = 0.f;
    for (int r = rstart; r < n; r += rstride) {
        float v = in[(size_t)r * CH + c];
        if (do_relu) v = fmaxf(v + bc, 0.f);
        s += v; s2 += v * v;
    }
    __shared__ float ls[256], ls2[256];
    ls[threadIdx.x] = s; ls2[threadIdx.x] = s2;
    __syncthreads();
    if (threadIdx.x < CH) {
        unsafeAtomicAdd(&sums[c],  ls[threadIdx.x] + ls[threadIdx.x + CH]);
        unsafeAtomicAdd(&sumsq[c], ls2[threadIdx.x] + ls2[threadIdx.x + CH]);
    }
}

__global__ void bnparam_kernel(const float* __restrict__ sums, const float* __restrict__ sumsq,
                               const float* __restrict__ gamma, const float* __restrict__ beta,
                               float* __restrict__ scale, float* __restrict__ shift, int n) {
    int c = threadIdx.x;
    if (c >= CH) return;
    float inv_n = 1.0f / (float)n;
    float mean = sums[c] * inv_n;
    float var  = sumsq[c] * inv_n - mean * mean;  // biased variance
    float sc = gamma[c] * rsqrtf(var + BN_EPS);
    scale[c] = sc;
    shift[c] = beta[c] - mean * sc;
}

// ---------------------------------------------------------------------------
// MFMA GEMM: H[row, j] = sum_k pre(A[row,k]) * W[j,k], H in bf16.
// pre(v) = (do_relu ? relu(v+bias[k]) : v) * scale[k] + shift[k], cast bf16.
// Block: 64 rows x 128 cols, 256 threads (4 waves x 16 rows). K=128 staged
// in LDS once. B-frags read from L2-resident Wb (bf16 [j][k] row-major).
// Layouts (gfx950, verified): A: m=lane&15, k=quad*8+j (16B/lane);
// B: n=lane&15, k=quad*8+j; D: col=lane&15, row=quad*4+reg.
// ---------------------------------------------------------------------------
#define GROWS 64
#define LDA 136  // bf16 elems; 272B row stride: 16B-aligned, 2-way banks (free)

__global__ __launch_bounds__(256) void gemm_mfma_kernel(
    const float* __restrict__ A, const float* __restrict__ bias, int do_relu,
    const float* __restrict__ scale, const float* __restrict__ shift,
    const __bf16* __restrict__ Wb, __bf16* __restrict__ Hout, int n) {
    __shared__ __bf16 As[GROWS][LDA];
    int tid = threadIdx.x;
    int row0 = blockIdx.x * GROWS;

    // ---- stage A: 64x128 fp32 -> BN -> bf16 LDS ----
    #pragma unroll
    for (int p = 0; p < 8; ++p) {
        int idx = p * 256 + tid;          // float4 index within tile (2048)
        int r = idx >> 5;                 // 32 float4 per row
        int f4 = idx & 31;
        int c4 = f4 * 4;
        int row = row0 + r;
        float4 v = make_float4(0.f, 0.f, 0.f, 0.f);
        if (row < n) v = ((const float4*)A)[(size_t)row * 32 + f4];
        float vv[4] = {v.x, v.y, v.z, v.w};
        __bf16 u[4];
        #pragma unroll
        for (int j = 0; j < 4; ++j) {
            int ch = c4 + j;
            float f = vv[j];
            if (do_relu) f = fmaxf(f + bias[ch], 0.f);
            f = f * scale[ch] + shift[ch];
            u[j] = (__bf16)f;
        }
        *(bf16x4*)&As[r][c4] = *(bf16x4*)u;
    }
    __syncthreads();

    // ---- MFMA ----
    int wv = tid >> 6;
    int lane = tid & 63;
    int m = lane & 15;
    int q = lane >> 4;
    int arow = wv * 16 + m;
    f32x4 acc[8] = {};
    #pragma unroll
    for (int kc = 0; kc < CH; kc += 32) {
        bf16x8 af = *(const bf16x8*)&As[arow][kc + q * 8];
        #pragma unroll
        for (int t = 0; t < 8; ++t) {
            bf16x8 bf = *(const bf16x8*)&Wb[(size_t)(t * 16 + m) * CH + kc + q * 8];
            acc[t] = __builtin_amdgcn_mfma_f32_16x16x32_bf16(af, bf, acc[t], 0, 0, 0);
        }
    }

    // ---- epilogue: D col=lane&15, row=quad*4+reg ----
    #pragma unroll
    for (int t = 0; t < 8; ++t) {
        #pragma unroll
        for (int r = 0; r < 4; ++r) {
            int row = row0 + wv * 16 + q * 4 + r;
            if (row < n) Hout[(size_t)row * CH + t * 16 + m] = (__bf16)acc[t][r];
        }
    }
}

// ---------------------------------------------------------------------------
// Gather aggregation over bf16 h: 32 threads/node, 4 ch/lane (8B loads),
// 8 nodes/block. acc fp32. final_mode: out = relu(acc+bias)+x.
// ---------------------------------------------------------------------------
__global__ __launch_bounds__(256) void agg_gather_kernel(
    const __bf16* __restrict__ h, const int* __restrict__ csr_src,
    const float* __restrict__ csr_norm, const int* __restrict__ offs,
    const float* __restrict__ dinv, const float* __restrict__ bias,
    const float* __restrict__ x, float* __restrict__ outbuf, int n, int final_mode) {
    int node = blockIdx.x * 8 + (threadIdx.x >> 5);
    if (node >= n) return;
    int c = (threadIdx.x & 31) * 4;
    float di = dinv[node];
    float w0 = di * di;
    bf16x4 hv = *(const bf16x4*)&h[(size_t)node * CH + c];
    float a0 = bf2f(hv[0]) * w0, a1 = bf2f(hv[1]) * w0,
          a2 = bf2f(hv[2]) * w0, a3 = bf2f(hv[3]) * w0;
    int e = offs[node], end = offs[node + 1];
    for (; e + 1 < end; e += 2) {
        int s0 = csr_src[e], s1 = csr_src[e + 1];
        float n0 = csr_norm[e], n1 = csr_norm[e + 1];
        bf16x4 v0 = *(const bf16x4*)&h[(size_t)s0 * CH + c];
        bf16x4 v1 = *(const bf16x4*)&h[(size_t)s1 * CH + c];
        a0 += bf2f(v0[0]) * n0; a1 += bf2f(v0[1]) * n0;
        a2 += bf2f(v0[2]) * n0; a3 += bf2f(v0[3]) * n0;
        a0 += bf2f(v1[0]) * n1; a1 += bf2f(v1[1]) * n1;
        a2 += bf2f(v1[2]) * n1; a3 += bf2f(v1[3]) * n1;
    }
    if (e < end) {
        int s0 = csr_src[e];
        float n0 = csr_norm[e];
        bf16x4 v0 = *(const bf16x4*)&h[(size_t)s0 * CH + c];
        a0 += bf2f(v0[0]) * n0; a1 += bf2f(v0[1]) * n0;
        a2 += bf2f(v0[2]) * n0; a3 += bf2f(v0[3]) * n0;
    }
    float4 o;
    if (final_mode) {
        float4 xb = ((const float4*)x)[(size_t)node * 32 + (c >> 2)];
        o.x = fmaxf(a0 + bias[c + 0], 0.f) + xb.x;
        o.y = fmaxf(a1 + bias[c + 1], 0.f) + xb.y;
        o.z = fmaxf(a2 + bias[c + 2], 0.f) + xb.z;
        o.w = fmaxf(a3 + bias[c + 3], 0.f) + xb.w;
    } else {
        o = make_float4(a0, a1, a2, a3);
    }
    ((float4*)outbuf)[(size_t)node * 32 + (c >> 2)] = o;
}

extern "C" void kernel_launch(void* const* d_in, const int* in_sizes, int n_in,
                              void* d_out, int out_size, void* d_ws, size_t ws_size,
                              hipStream_t stream) {
    const float* x      = (const float*)d_in[0];
    const int*   eidx   = (const int*)d_in[1];
    const float* W1     = (const float*)d_in[2];
    const float* b1     = (const float*)d_in[3];
    const float* W2     = (const float*)d_in[4];
    const float* b2     = (const float*)d_in[5];
    const float* gamma1 = (const float*)d_in[6];
    const float* beta1  = (const float*)d_in[7];
    const float* gamma2 = (const float*)d_in[8];
    const float* beta2  = (const float*)d_in[9];
    float* out = (float*)d_out;

    const int N = in_sizes[0] / CH;
    const int E = in_sizes[1] / 2;
    const int* src = eidx;
    const int* dst = eidx + E;

    char* ws = (char*)d_ws;
    size_t off = 0;
    auto carve = [&](size_t bytes) { char* p = ws + off; off = (off + bytes + 1023) & ~(size_t)1023; return p; };
    int*    cnt     = (int*)carve((size_t)N * 4);
    float*  dinv    = (float*)carve((size_t)N * 4);
    int*    offs    = (int*)carve((size_t)(N + 1) * 4);
    int*    fillc   = (int*)carve((size_t)N * 4);
    int*    bsum    = (int*)carve(1024 * 4);
    float*  small   = (float*)carve(8 * CH * 4);
    int*    csr_src = (int*)carve((size_t)E * 4);
    float*  csr_nrm = (float*)carve((size_t)E * 4);
    __bf16* W1b     = (__bf16*)carve((size_t)CH * CH * 2);
    __bf16* W2b     = (__bf16*)carve((size_t)CH * CH * 2);
    __bf16* h_bf    = (__bf16*)carve((size_t)N * CH * 2);
    float*  agg_buf = (float*)carve((size_t)N * CH * 4);
    float* sums1  = small + 0 * CH;
    float* sumsq1 = small + 1 * CH;
    float* sums2  = small + 2 * CH;
    float* sumsq2 = small + 3 * CH;
    float* scale1 = small + 4 * CH;
    float* shift1 = small + 5 * CH;
    float* scale2 = small + 6 * CH;
    float* shift2 = small + 7 * CH;
    (void)ws_size; (void)n_in; (void)out_size;

    hipMemsetAsync(cnt, 0, (size_t)N * 4, stream);
    hipMemsetAsync(fillc, 0, (size_t)N * 4, stream);
    hipMemsetAsync(small, 0, 8 * CH * 4, stream);

    // ---- graph prep: degrees + CSR + bf16 weights ----
    count_kernel<<<(E + 255) / 256, 256, 0, stream>>>(dst, cnt, E);
    dinv_kernel<<<(N + 255) / 256, 256, 0, stream>>>(cnt, dinv, N);
    int nb = (N + 1023) / 1024;
    scan1_kernel<<<nb, 256, 0, stream>>>(cnt, offs, bsum, N);
    scan2_kernel<<<1, 256, 0, stream>>>(bsum, nb);
    scan3_kernel<<<(N + 255) / 256, 256, 0, stream>>>(offs, bsum, N, E);
    fill_kernel<<<(E + 255) / 256, 256, 0, stream>>>(src, dst, offs, fillc, dinv, csr_src, csr_nrm, E);
    wprep_kernel<<<(CH * CH + 255) / 256, 256, 0, stream>>>(W1, W1b, CH * CH);
    wprep_kernel<<<(CH * CH + 255) / 256, 256, 0, stream>>>(W2, W2b, CH * CH);

    // ---- stage 1 ----
    stats_kernel<<<784, 256, 0, stream>>>(x, nullptr, 0, sums1, sumsq1, N);
    bnparam_kernel<<<1, CH, 0, stream>>>(sums1, sumsq1, gamma1, beta1, scale1, shift1, N);
    gemm_mfma_kernel<<<(N + GROWS - 1) / GROWS, 256, 0, stream>>>(x, nullptr, 0, scale1, shift1, W1b, h_bf, N);
    agg_gather_kernel<<<(N + 7) / 8, 256, 0, stream>>>(h_bf, csr_src, csr_nrm, offs, dinv,
                                                       nullptr, nullptr, agg_buf, N, 0);

    // ---- stage 2 (final epilogue fused into aggregation) ----
    stats_kernel<<<784, 256, 0, stream>>>(agg_buf, b1, 1, sums2, sumsq2, N);
    bnparam_kernel<<<1, CH, 0, stream>>>(sums2, sumsq2, gamma2, beta2, scale2, shift2, N);
    gemm_mfma_kernel<<<(N + GROWS - 1) / GROWS, 256, 0, stream>>>(agg_buf, b1, 1, scale2, shift2, W2b, h_bf, N);
    agg_gather_kernel<<<(N + 7) / 8, 256, 0, stream>>>(h_bf, csr_src, csr_nrm, offs, dinv,
                                                       b2, x, out, N, 1);
}